// Round 5
// baseline (342.256 us; speedup 1.0000x reference)
//
#include <hip/hip_runtime.h>

// Mamba selective scan: h_t = exp(delta_t*A)*h_{t-1} + delta_t*B_t*u_t ; y_t = C_t*h_t
// 3-pass hierarchical scan. Round-5: the round-4 software pipeline was undone by
// the scheduler (VGPR=32 -> loads sunk to just-in-time, ~1 outstanding load/wave,
// ~3 TB/s HBM). Pin program order with sched_barrier(0) per unrolled step so the
// depth-2 prefetch survives: loads for stage t+2 issue before the barrier, the
// scan_step for stage t consumes after it -> compiler emits counted vmcnt(6),
// ~9 loads in flight per wave.

#define BB 8
#define SS 4096
#define DD 1024
#define TT 16
#define NCHUNK (SS / TT)          // 256 chunks per chain
#define NBLK   (BB * NCHUNK)      // 2048 blocks, 256 thr (thread = 4 channels)

typedef __attribute__((ext_vector_type(4))) float f32x4;

__device__ __forceinline__ float4 ld4(const float* __restrict__ p) {
    return *(const float4*)p;
}

__device__ __forceinline__ void scan_step(float4& h, float4& p,
                                          const float4 dt, const float4 bv,
                                          const float4 uv, const float4 Av) {
    float a;
    a = __expf(dt.x * Av.x); h.x = fmaf(a, h.x, dt.x * bv.x * uv.x); p.x *= a;
    a = __expf(dt.y * Av.y); h.y = fmaf(a, h.y, dt.y * bv.y * uv.y); p.y *= a;
    a = __expf(dt.z * Av.z); h.z = fmaf(a, h.z, dt.z * bv.z * uv.z); p.z *= a;
    a = __expf(dt.w * Av.w); h.w = fmaf(a, h.w, dt.w * bv.w * uv.w); p.w *= a;
}

// K3 variant: no running product needed.
__device__ __forceinline__ void scan_step_np(float4& h,
                                             const float4 dt, const float4 bv,
                                             const float4 uv, const float4 Av) {
    float a;
    a = __expf(dt.x * Av.x); h.x = fmaf(a, h.x, dt.x * bv.x * uv.x);
    a = __expf(dt.y * Av.y); h.y = fmaf(a, h.y, dt.y * bv.y * uv.y);
    a = __expf(dt.z * Av.z); h.z = fmaf(a, h.z, dt.z * bv.z * uv.z);
    a = __expf(dt.w * Av.w); h.w = fmaf(a, h.w, dt.w * bv.w * uv.w);
}

__global__ __launch_bounds__(256, 8) void k1_local(
    const float* __restrict__ u, const float* __restrict__ delta,
    const float* __restrict__ A, const float* __restrict__ Bm,
    float* __restrict__ aggA, float* __restrict__ aggB)
{
    const int c = blockIdx.x % NCHUNK;
    const int b = blockIdx.x / NCHUNK;
    const int d4 = threadIdx.x << 2;

    const float4 Av = ld4(A + d4);
    const size_t base = ((size_t)(b * SS + c * TT)) * DD + d4;

    float4 h = {0.f, 0.f, 0.f, 0.f};
    float4 p = {1.f, 1.f, 1.f, 1.f};

    // 3-stage ring; indices are compile-time after full unroll (rule #20).
    float4 dt[3], bv[3], uv[3];
    dt[0] = ld4(delta + base);      bv[0] = ld4(Bm + base);      uv[0] = ld4(u + base);
    dt[1] = ld4(delta + base + DD); bv[1] = ld4(Bm + base + DD); uv[1] = ld4(u + base + DD);
#pragma unroll
    for (int t = 0; t < TT; ++t) {
        if (t + 2 < TT) {
            const int s2 = (t + 2) % 3;
            const size_t i2 = base + (size_t)(t + 2) * DD;
            dt[s2] = ld4(delta + i2);
            bv[s2] = ld4(Bm + i2);
            uv[s2] = ld4(u + i2);
        }
        // Pin: stage t+2 loads must be emitted above; scan_step(t) below.
        __builtin_amdgcn_sched_barrier(0);
        const int s = t % 3;
        scan_step(h, p, dt[s], bv[s], uv[s], Av);
    }
    const size_t o = ((size_t)(b * NCHUNK + c)) * DD + d4;
    *(float4*)(aggA + o) = p;
    *(float4*)(aggB + o) = h;
}

// Thread-per-chain sequential scan of chunk aggregates -> exclusive prefixes.
__global__ __launch_bounds__(64) void k2_scan(
    const float* __restrict__ aggA, const float* __restrict__ aggB,
    float* __restrict__ pref)
{
    const int b = blockIdx.x >> 4;                          // 8 batches
    const int d = ((blockIdx.x & 15) << 6) + threadIdx.x;   // 16 groups of 64
    const size_t base = (size_t)b * NCHUNK * DD + (size_t)d;

    float X = 0.f;
#pragma unroll 8
    for (int c = 0; c < NCHUNK; ++c) {
        const size_t o = base + (size_t)c * DD;
        pref[o] = X;
        X = fmaf(aggA[o], X, aggB[o]);
    }
}

__global__ __launch_bounds__(256) void k3_apply(
    const float* __restrict__ u, const float* __restrict__ delta,
    const float* __restrict__ A, const float* __restrict__ Bm,
    const float* __restrict__ Cm, const float* __restrict__ pref,
    float* __restrict__ out)
{
    const int c = blockIdx.x % NCHUNK;
    const int b = blockIdx.x / NCHUNK;
    const int d4 = threadIdx.x << 2;

    const float4 Av = ld4(A + d4);
    float4 h = ld4(pref + ((size_t)(b * NCHUNK + c)) * DD + d4);
    const size_t base = ((size_t)(b * SS + c * TT)) * DD + d4;

    // depth-2 ring for delta/B/u, depth-1 for C.
    float4 dt[3], bv[3], uv[3], cv[2];
    dt[0] = ld4(delta + base);      bv[0] = ld4(Bm + base);      uv[0] = ld4(u + base);
    dt[1] = ld4(delta + base + DD); bv[1] = ld4(Bm + base + DD); uv[1] = ld4(u + base + DD);
    cv[0] = ld4(Cm + base);
#pragma unroll
    for (int t = 0; t < TT; ++t) {
        if (t + 2 < TT) {
            const int s2 = (t + 2) % 3;
            const size_t i2 = base + (size_t)(t + 2) * DD;
            dt[s2] = ld4(delta + i2);
            bv[s2] = ld4(Bm + i2);
            uv[s2] = ld4(u + i2);
        }
        if (t + 1 < TT) cv[(t + 1) % 2] = ld4(Cm + base + (size_t)(t + 1) * DD);
        __builtin_amdgcn_sched_barrier(0);
        const int s = t % 3;
        scan_step_np(h, dt[s], bv[s], uv[s], Av);
        const float4 c4 = cv[t % 2];
        f32x4 y;
        y.x = c4.x * h.x; y.y = c4.y * h.y; y.z = c4.z * h.z; y.w = c4.w * h.w;
        __builtin_nontemporal_store(y, (f32x4*)(out + base + (size_t)t * DD));
    }
}

extern "C" void kernel_launch(void* const* d_in, const int* in_sizes, int n_in,
                              void* d_out, int out_size, void* d_ws, size_t ws_size,
                              hipStream_t stream) {
    (void)in_sizes; (void)n_in; (void)out_size; (void)ws_size;
    const float* u     = (const float*)d_in[0];
    const float* delta = (const float*)d_in[1];
    const float* A     = (const float*)d_in[2];
    const float* Bm    = (const float*)d_in[3];
    const float* Cm    = (const float*)d_in[4];
    float* out = (float*)d_out;

    float* ws = (float*)d_ws;
    const size_t n = (size_t)BB * NCHUNK * DD;   // 2M floats = 8 MB per buffer
    float* aggA = ws;
    float* aggB = ws + n;
    float* pref = ws + 2 * n;

    k1_local<<<NBLK, 256, 0, stream>>>(u, delta, A, Bm, aggA, aggB);
    k2_scan<<<BB * (DD / 64), 64, 0, stream>>>(aggA, aggB, pref);
    k3_apply<<<NBLK, 256, 0, stream>>>(u, delta, A, Bm, Cm, pref, out);
}

// Round 7
// 275.141 us; speedup vs baseline: 1.2439x; 1.2439x over previous
//
#include <hip/hip_runtime.h>

// Mamba selective scan: h_t = exp(delta_t*A)*h_{t-1} + delta_t*B_t*u_t ; y_t = C_t*h_t
// 3-pass hierarchical scan, all fp32 (round-6 fp16 packing failed validation and
// is abandoned). Round-7 levers:
//  1) Two independent chunks per thread in K1/K3: two independent dependence
//     chains let the scheduler overlap chain-0 loads with chain-1 compute
//     (rounds 3-5 proved it will not pipeline a single serial chain; measured
//     in-flight ~0.26 wave-loads/wave -> 4.2 TB/s).
//  2) K3 dispatch order globally REVERSED vs K1's read order: K1's LIFO tail
//     (~256 MB of delta/B/u) is L3-resident; K3 consumes it before eviction.
//     C uses nontemporal loads and out nontemporal stores to protect the residue.
//  3) K2 unroll-32 (latency-bound serial chain over L3-resident aggregates).

#define BB 8
#define SS 4096
#define DD 1024
#define TT 16
#define NCHUNK (SS / TT)            // 256 chunks per chain
#define NPAIR  (NCHUNK / 2)         // 128 chunk-pairs
#define NBLK2  (BB * NPAIR)         // 1024 blocks for K1/K3

typedef __attribute__((ext_vector_type(4))) float f32x4;

__device__ __forceinline__ f32x4 ld4(const float* __restrict__ p) {
    return *(const f32x4*)p;
}
__device__ __forceinline__ f32x4 ntld4(const float* __restrict__ p) {
    return __builtin_nontemporal_load((const f32x4*)p);
}

// one scan step on a float4 channel group, with running product
__device__ __forceinline__ void step_p(f32x4& h, f32x4& p,
                                       const f32x4 dt, const f32x4 bv,
                                       const f32x4 uv, const f32x4 Av) {
    float a;
    a = __expf(dt.x * Av.x); h.x = fmaf(a, h.x, dt.x * bv.x * uv.x); p.x *= a;
    a = __expf(dt.y * Av.y); h.y = fmaf(a, h.y, dt.y * bv.y * uv.y); p.y *= a;
    a = __expf(dt.z * Av.z); h.z = fmaf(a, h.z, dt.z * bv.z * uv.z); p.z *= a;
    a = __expf(dt.w * Av.w); h.w = fmaf(a, h.w, dt.w * bv.w * uv.w); p.w *= a;
}
// without product (K3)
__device__ __forceinline__ void step_np(f32x4& h,
                                        const f32x4 dt, const f32x4 bv,
                                        const f32x4 uv, const f32x4 Av) {
    float a;
    a = __expf(dt.x * Av.x); h.x = fmaf(a, h.x, dt.x * bv.x * uv.x);
    a = __expf(dt.y * Av.y); h.y = fmaf(a, h.y, dt.y * bv.y * uv.y);
    a = __expf(dt.z * Av.z); h.z = fmaf(a, h.z, dt.z * bv.z * uv.z);
    a = __expf(dt.w * Av.w); h.w = fmaf(a, h.w, dt.w * bv.w * uv.w);
}

__global__ __launch_bounds__(256) void k1_local(
    const float* __restrict__ u, const float* __restrict__ delta,
    const float* __restrict__ A, const float* __restrict__ Bm,
    float* __restrict__ aggA, float* __restrict__ aggB)
{
    const int pair = blockIdx.x % NPAIR;
    const int b    = blockIdx.x / NPAIR;
    const int c0   = pair * 2;               // chunks c0, c0+1
    const int d4   = threadIdx.x << 2;

    const f32x4 Av = ld4(A + d4);
    size_t i0 = ((size_t)(b * SS + c0 * TT)) * DD + d4;
    size_t i1 = i0 + (size_t)TT * DD;

    f32x4 h0 = {0.f,0.f,0.f,0.f}, p0 = {1.f,1.f,1.f,1.f};
    f32x4 h1 = {0.f,0.f,0.f,0.f}, p1 = {1.f,1.f,1.f,1.f};
#pragma unroll
    for (int t = 0; t < TT; ++t, i0 += DD, i1 += DD) {
        const f32x4 dt0 = ld4(delta + i0), dt1 = ld4(delta + i1);
        const f32x4 bv0 = ld4(Bm + i0),    bv1 = ld4(Bm + i1);
        const f32x4 uv0 = ld4(u + i0),     uv1 = ld4(u + i1);
        step_p(h0, p0, dt0, bv0, uv0, Av);
        step_p(h1, p1, dt1, bv1, uv1, Av);
    }
    const size_t o0 = ((size_t)(b * NCHUNK + c0)) * DD + d4;
    *(f32x4*)(aggA + o0) = p0;
    *(f32x4*)(aggB + o0) = h0;
    *(f32x4*)(aggA + o0 + DD) = p1;
    *(f32x4*)(aggB + o0 + DD) = h1;
}

// Thread-per-chain sequential scan of chunk aggregates -> exclusive prefixes.
// Aggregates are L3-resident (24 MB, just written); unroll-32 batches loads.
__global__ __launch_bounds__(64) void k2_scan(
    const float* __restrict__ aggA, const float* __restrict__ aggB,
    float* __restrict__ pref)
{
    const int b = blockIdx.x >> 4;                          // 8 batches
    const int d = ((blockIdx.x & 15) << 6) + threadIdx.x;   // 16 groups of 64
    const size_t base = (size_t)b * NCHUNK * DD + (size_t)d;

    float X = 0.f;
#pragma unroll 32
    for (int c = 0; c < NCHUNK; ++c) {
        const size_t o = base + (size_t)c * DD;
        pref[o] = X;
        X = fmaf(aggA[o], X, aggB[o]);
    }
}

__global__ __launch_bounds__(256) void k3_apply(
    const float* __restrict__ u, const float* __restrict__ delta,
    const float* __restrict__ A, const float* __restrict__ Bm,
    const float* __restrict__ Cm, const float* __restrict__ pref,
    float* __restrict__ out)
{
    // Global dispatch reversal: first-dispatched block touches the data K1
    // read LAST (b=7, highest chunk) -> consumes the L3 residue LIFO.
    const int rbid = (NBLK2 - 1) - blockIdx.x;
    const int pair = rbid % NPAIR;
    const int b    = rbid / NPAIR;
    const int c0   = pair * 2;
    const int d4   = threadIdx.x << 2;

    const f32x4 Av = ld4(A + d4);
    const size_t o0 = ((size_t)(b * NCHUNK + c0)) * DD + d4;
    f32x4 h0 = ld4(pref + o0);
    f32x4 h1 = ld4(pref + o0 + DD);

    size_t i0 = ((size_t)(b * SS + c0 * TT)) * DD + d4;
    size_t i1 = i0 + (size_t)TT * DD;
#pragma unroll
    for (int t = 0; t < TT; ++t, i0 += DD, i1 += DD) {
        const f32x4 dt0 = ld4(delta + i0), dt1 = ld4(delta + i1);
        const f32x4 bv0 = ld4(Bm + i0),    bv1 = ld4(Bm + i1);
        const f32x4 uv0 = ld4(u + i0),     uv1 = ld4(u + i1);
        const f32x4 cv0 = ntld4(Cm + i0),  cv1 = ntld4(Cm + i1);
        step_np(h0, dt0, bv0, uv0, Av);
        step_np(h1, dt1, bv1, uv1, Av);
        f32x4 y0, y1;
        y0.x = cv0.x * h0.x; y0.y = cv0.y * h0.y; y0.z = cv0.z * h0.z; y0.w = cv0.w * h0.w;
        y1.x = cv1.x * h1.x; y1.y = cv1.y * h1.y; y1.z = cv1.z * h1.z; y1.w = cv1.w * h1.w;
        __builtin_nontemporal_store(y0, (f32x4*)(out + i0));
        __builtin_nontemporal_store(y1, (f32x4*)(out + i1));
    }
}

extern "C" void kernel_launch(void* const* d_in, const int* in_sizes, int n_in,
                              void* d_out, int out_size, void* d_ws, size_t ws_size,
                              hipStream_t stream) {
    (void)in_sizes; (void)n_in; (void)out_size; (void)ws_size;
    const float* u     = (const float*)d_in[0];
    const float* delta = (const float*)d_in[1];
    const float* A     = (const float*)d_in[2];
    const float* Bm    = (const float*)d_in[3];
    const float* Cm    = (const float*)d_in[4];
    float* out = (float*)d_out;

    float* ws = (float*)d_ws;
    const size_t n = (size_t)BB * NCHUNK * DD;   // 2M floats = 8 MB per buffer
    float* aggA = ws;
    float* aggB = ws + n;
    float* pref = ws + 2 * n;

    k1_local<<<NBLK2, 256, 0, stream>>>(u, delta, A, Bm, aggA, aggB);
    k2_scan<<<BB * (DD / 64), 64, 0, stream>>>(aggA, aggB, pref);
    k3_apply<<<NBLK2, 256, 0, stream>>>(u, delta, A, Bm, Cm, pref, out);
}